// Round 5
// baseline (855.143 us; speedup 1.0000x reference)
//
#include <hip/hip_runtime.h>

#define NBLK 256
#define NTHR 512

typedef __attribute__((ext_vector_type(8))) short s16x8;
typedef __attribute__((ext_vector_type(8))) __bf16 bf16x8;
typedef __attribute__((ext_vector_type(4))) float f32x4;

template <bool B> struct BoolC { static constexpr bool value = B; };

__device__ __forceinline__ ushort f2bf(float f) {
  uint u = __float_as_uint(f);
  return (ushort)((u + 0x7FFFu + ((u >> 16) & 1u)) >> 16);  // RNE
}
__device__ __forceinline__ float bf2f(ushort s) {
  return __uint_as_float(((uint)s) << 16);
}
__device__ __forceinline__ float sigm(float x) { return 1.f / (1.f + __expf(-x)); }
__device__ __forceinline__ float tanhf_(float x) {
  x = fminf(9.f, fmaxf(-9.f, x));
  float e = __expf(2.f * x);
  return (e - 1.f) / (e + 1.f);
}

// ---------------- init: zero flags + handshake words ----------------
__global__ void init_k(uint* __restrict__ bar) {
  int i = blockIdx.x * blockDim.x + threadIdx.x;
  if (i < 512) bar[i] = 0u;  // [0,256): flags 16g x 16; [256,384): per-group {mask,cnt} x8
}

// ---------------- transpose/concat x,y -> xyT[t][b][0:512] bf16 (coalesced) ----------------
__global__ void xyt_k(const float* __restrict__ x, const float* __restrict__ y,
                      ushort* __restrict__ xyT) {
  __shared__ ushort sT[64 * 130];
  const int bid = blockIdx.x;      // 2048 = 256 b x 8 chunks
  const int chunk = bid & 7;       // 0..3 -> x, 4..7 -> y
  const int b = bid >> 3;
  const int d0 = (chunk & 3) * 64;
  const float* src = ((chunk < 4) ? x : y) + ((size_t)b * 256 + d0) * 128;
  const int tid = threadIdx.x;
  const int tt = tid & 127, rr = tid >> 7;
#pragma unroll
  for (int i = 0; i < 32; ++i) {
    int row = i * 2 + rr;
    sT[row * 130 + tt] = f2bf(src[(size_t)row * 128 + tt]);
  }
  __syncthreads();
  const int dbase = ((chunk < 4) ? 0 : 256) + d0;
#pragma unroll
  for (int i = 0; i < 16; ++i) {
    int idx = tid + i * 256;
    int t = idx >> 5, j = idx & 31;
    uint v = (uint)sT[(2 * j) * 130 + t] | ((uint)sT[(2 * j + 1) * 130 + t] << 16);
    *(uint*)(xyT + ((size_t)t * 256 + b) * 512 + dbase + 2 * j) = v;
  }
}

// ---------------- persistent sequential LSTM kernel (layer 1 only) ----------------
// bid: mt = bid&7 (row tile; == XCD under round-robin), cg = (bid>>3)&15, s = bid>>7.
// Sync group = 16 blocks sharing (s, mt). Startup handshake measures whether the
// group is XCD-co-resident: fast path = agent-scope L2 exchange (sc0), fallback =
// system-scope LLC exchange (sc0|sc1). Correctness never depends on placement.
// LDS: [0,32K) xybuf0 | [32K,64K) xybuf1 | [64K,96K) hLDS | [96K,+18.4K) sAcc | coh word
__launch_bounds__(NTHR, 2)
__global__ void seq_k(const ushort* __restrict__ xyT, ushort* __restrict__ hbuf,
                      ushort* __restrict__ hist,
                      const float* __restrict__ WTg, const float* __restrict__ WFg,
                      const float* __restrict__ WTc, const float* __restrict__ WFc,
                      const float* __restrict__ bTg, const float* __restrict__ bFg,
                      const float* __restrict__ bTc, const float* __restrict__ bFc,
                      uint* bar) {
  extern __shared__ char smem[];
  float* sAcc = (float*)(smem + 98304);
  uint* sCoh = (uint*)(smem + 116736);

  const int tid = threadIdx.x;
  const int bid = blockIdx.x;
  const int mt = bid & 7;
  const int cg = (bid >> 3) & 15;
  const int s = bid >> 7;
  const int g = s * 8 + mt;
  const int m0 = mt * 32;
  const int j0 = cg * 32;
  const int w = tid >> 6;
  const int l = tid & 63;
  const int l15 = l & 15;
  const int q16 = (l >> 4) * 16;  // byte offset of k-octet
  const bool isGate = (w < 6);
  uint* fl = bar + (g << 4);

  // ---- startup handshake: is this sync group co-resident on one XCD? ----
  {
    uint xcc = __builtin_amdgcn_s_getreg((3u << 11) | 20u) & 15u;  // HW_REG_XCC_ID
    uint* gw = bar + 256 + (g << 3);                               // {mask, cnt}
    if (tid == 0) {
      __hip_atomic_fetch_or(gw, 1u << xcc, __ATOMIC_RELAXED, __HIP_MEMORY_SCOPE_SYSTEM);
      __hip_atomic_fetch_add(gw + 1, 1u, __ATOMIC_RELEASE, __HIP_MEMORY_SCOPE_SYSTEM);
      while (__hip_atomic_load(gw + 1, __ATOMIC_RELAXED, __HIP_MEMORY_SCOPE_SYSTEM) < 16u)
        __builtin_amdgcn_s_sleep(8);
      uint mask = __hip_atomic_load(gw, __ATOMIC_RELAXED, __HIP_MEMORY_SCOPE_SYSTEM);
      sCoh[0] = (uint)(__popc(mask) == 1);
    }
  }

  // ---- persistent weight fragments in VGPRs (layer 1 = offset 1) ----
  s16x8 wreg[32];
  if (isGate) {
    const int gt = w >> 1, half = w & 1;
    const float* Wp = ((s == 0) ? WTg : WFg) + 1572864
                    + ((size_t)(gt * 512 + j0 + half * 16 + l15)) * 1024 + (q16 >> 1);
#pragma unroll
    for (int kk = 0; kk < 32; ++kk) {
      s16x8 v;
#pragma unroll
      for (int e = 0; e < 8; ++e) v[e] = (short)f2bf(Wp[kk * 32 + e]);
      wreg[kk] = v;
    }
  } else {
    const int half = w & 1;
    const float* Wp = ((s == 0) ? WTc : WFc) + 393216
                    + ((size_t)(j0 + half * 16 + l15)) * 768 + (q16 >> 1);
#pragma unroll
    for (int kk = 0; kk < 24; ++kk) {
      s16x8 v;
#pragma unroll
      for (int e = 0; e < 8; ++e) v[e] = (short)f2bf(Wp[kk * 32 + e]);
      wreg[kk] = v;
    }
  }

  // ---- per-thread elementwise constants + register-resident cell state ----
  const int ro = tid >> 4;         // row 0..31
  const int cc0 = (tid & 15) * 2;  // col pair
  const int ehalf = cc0 >> 4;
  const int ec16 = cc0 & 15;
  float bfv0, bfv1, biv0, biv1, bov0, bov1, bcv0, bcv1;
  {
    const float* bg = ((s == 0) ? bTg : bFg) + 1536;
    const float* bc = ((s == 0) ? bTc : bFc) + 512;
    int col = j0 + cc0;
    bfv0 = bg[col];        bfv1 = bg[col + 1];
    biv0 = bg[512 + col];  biv1 = bg[513 + col];
    bov0 = bg[1024 + col]; bov1 = bg[1025 + col];
    bcv0 = bc[col];        bcv1 = bc[col + 1];
  }
  float C0 = 0.f, C1 = 0.f;

  // stage one 1024B row; XOR-swizzled source, linear LDS dest (cached, for xyT)
  auto stage_row = [&](const ushort* gbase, char* lbase, int r) {
    const char* srow = (const char*)(gbase + (size_t)r * 512);
    int off = (l * 16) ^ ((r & 7) << 4);
    __builtin_amdgcn_global_load_lds(
        (const __attribute__((address_space(1))) void*)(srow + off),
        (__attribute__((address_space(3))) void*)(lbase + (r << 10)), 16, 0, 0);
  };

  // prestage xy(0) into buf0
  {
#pragma unroll
    for (int i = 0; i < 4; ++i) stage_row(xyT + (size_t)m0 * 512, smem, (w << 2) + i);
  }
  __syncthreads();
  const bool fastCoh = (sCoh[0] != 0);

  const int sw = (l15 & 7) << 4;

  auto run = [&](auto FASTC) {
    constexpr bool F = decltype(FASTC)::value;
    constexpr int SCOPE = F ? __HIP_MEMORY_SCOPE_AGENT : __HIP_MEMORY_SCOPE_SYSTEM;

    auto stage_row_h = [&](const ushort* gbase, char* lbase, int r) {
      const char* srow = (const char*)(gbase + (size_t)r * 512);
      int off = (l * 16) ^ ((r & 7) << 4);
      if constexpr (F)
        __builtin_amdgcn_global_load_lds(
            (const __attribute__((address_space(1))) void*)(srow + off),
            (__attribute__((address_space(3))) void*)(lbase + (r << 10)), 16, 0, 1);   // sc0
      else
        __builtin_amdgcn_global_load_lds(
            (const __attribute__((address_space(1))) void*)(srow + off),
            (__attribute__((address_space(3))) void*)(lbase + (r << 10)), 16, 0, 17);  // sc0|sc1
    };

    for (int t = 0; t < 128; ++t) {
      const int cur = t & 1;
      char* xyb = smem + cur * 32768;
      char* xybn = smem + (cur ^ 1) * 32768;
      char* hb = smem + 65536;

      f32x4 acc0 = {0.f, 0.f, 0.f, 0.f};
      f32x4 acc1 = {0.f, 0.f, 0.f, 0.f};

      // A: xy-half MFMAs (data staged last step; no cross-block dependency)
      {
        const char* base0 = xyb + (l15 << 10);
        const char* base1 = xyb + ((16 + l15) << 10);
        if (isGate) {
#pragma unroll
          for (int kk = 0; kk < 16; ++kk) {
            int c2 = (kk * 64 + q16) ^ sw;
            s16x8 a0 = *(const s16x8*)(base0 + c2);
            s16x8 a1 = *(const s16x8*)(base1 + c2);
            acc0 = __builtin_amdgcn_mfma_f32_16x16x32_bf16(
                __builtin_bit_cast(bf16x8, a0), __builtin_bit_cast(bf16x8, wreg[kk]), acc0, 0, 0, 0);
            acc1 = __builtin_amdgcn_mfma_f32_16x16x32_bf16(
                __builtin_bit_cast(bf16x8, a1), __builtin_bit_cast(bf16x8, wreg[kk]), acc1, 0, 0, 0);
          }
        } else {
#pragma unroll
          for (int kk = 0; kk < 8; ++kk) {
            int c2 = ((s * 512 + kk * 64 + q16)) ^ sw;
            s16x8 a0 = *(const s16x8*)(base0 + c2);
            s16x8 a1 = *(const s16x8*)(base1 + c2);
            acc0 = __builtin_amdgcn_mfma_f32_16x16x32_bf16(
                __builtin_bit_cast(bf16x8, a0), __builtin_bit_cast(bf16x8, wreg[kk]), acc0, 0, 0, 0);
            acc1 = __builtin_amdgcn_mfma_f32_16x16x32_bf16(
                __builtin_bit_cast(bf16x8, a1), __builtin_bit_cast(bf16x8, wreg[kk]), acc1, 0, 0, 0);
          }
        }
      }

      // B: waves 1..7 prefetch their xy(t+1) rows (cached; L2 stays warm)
      const int tn = (t < 127) ? t + 1 : 127;
      const ushort* xyNext = xyT + ((size_t)(tn * 256 + m0)) * 512;
      if (w != 0) {
#pragma unroll
        for (int i = 0; i < 4; ++i) stage_row(xyNext, xybn, (w << 2) + i);
      }

      // C: wave 0 only: relaxed poll of the 16 group flags (no fences, no inv)
      if (w == 0 && t) {
        const uint tgt = (uint)t;
        while (true) {
          uint v = (l < 16) ? __hip_atomic_load(fl + l, __ATOMIC_RELAXED, SCOPE) : tgt;
          if (__all((int)(v >= tgt))) break;
          __builtin_amdgcn_s_sleep(1);
        }
      }
      __syncthreads();

      // D: stage h(t) first (critical), then wave 0's deferred xy prefetch
      if (t) {
        const ushort* hsrc = hbuf + ((size_t)((cur * 2 + s) * 256 + m0)) * 512;
#pragma unroll
        for (int i = 0; i < 4; ++i) stage_row_h(hsrc, hb, (w << 2) + i);
      }
      if (w == 0) {
#pragma unroll
        for (int i = 0; i < 4; ++i) stage_row(xyNext, xybn, i);
      }

      // E: drain staging + block barrier
      __syncthreads();

      // F: h-half MFMAs (skipped at t=0: h(0)=0)
      if (t) {
        const char* base0 = hb + (l15 << 10);
        const char* base1 = hb + ((16 + l15) << 10);
        if (isGate) {
#pragma unroll
          for (int kk = 0; kk < 16; ++kk) {
            int c2 = (kk * 64 + q16) ^ sw;
            s16x8 a0 = *(const s16x8*)(base0 + c2);
            s16x8 a1 = *(const s16x8*)(base1 + c2);
            acc0 = __builtin_amdgcn_mfma_f32_16x16x32_bf16(
                __builtin_bit_cast(bf16x8, a0), __builtin_bit_cast(bf16x8, wreg[16 + kk]), acc0, 0, 0, 0);
            acc1 = __builtin_amdgcn_mfma_f32_16x16x32_bf16(
                __builtin_bit_cast(bf16x8, a1), __builtin_bit_cast(bf16x8, wreg[16 + kk]), acc1, 0, 0, 0);
          }
        } else {
#pragma unroll
          for (int kk = 0; kk < 16; ++kk) {
            int c2 = (kk * 64 + q16) ^ sw;
            s16x8 a0 = *(const s16x8*)(base0 + c2);
            s16x8 a1 = *(const s16x8*)(base1 + c2);
            acc0 = __builtin_amdgcn_mfma_f32_16x16x32_bf16(
                __builtin_bit_cast(bf16x8, a0), __builtin_bit_cast(bf16x8, wreg[8 + kk]), acc0, 0, 0, 0);
            acc1 = __builtin_amdgcn_mfma_f32_16x16x32_bf16(
                __builtin_bit_cast(bf16x8, a1), __builtin_bit_cast(bf16x8, wreg[8 + kk]), acc1, 0, 0, 0);
          }
        }
      }

      // G: acc -> sAcc (row stride 18 floats)
#pragma unroll
      for (int rg = 0; rg < 4; ++rg) {
        sAcc[w * 576 + ((q16 >> 2) + rg) * 18 + l15] = acc0[rg];
        sAcc[w * 576 + (16 + (q16 >> 2) + rg) * 18 + l15] = acc1[rg];
      }
      __syncthreads();

      // H: elementwise LSTM update (C in registers); h stores to group coherence point
      {
        const float2 pf = *(const float2*)&sAcc[(0 + ehalf) * 576 + ro * 18 + ec16];
        const float2 pi = *(const float2*)&sAcc[(2 + ehalf) * 576 + ro * 18 + ec16];
        const float2 po = *(const float2*)&sAcc[(4 + ehalf) * 576 + ro * 18 + ec16];
        const float2 pc = *(const float2*)&sAcc[(6 + ehalf) * 576 + ro * 18 + ec16];
        float f0 = sigm(pf.x + bfv0), f1 = sigm(pf.y + bfv1);
        float i0 = sigm(pi.x + biv0), i1 = sigm(pi.y + biv1);
        float o0 = sigm(po.x + bov0), o1 = sigm(po.y + bov1);
        float c0 = tanhf_(pc.x + bcv0), c1 = tanhf_(pc.y + bcv1);
        C0 = f0 * C0 + i0 * c0;
        C1 = f1 * C1 + i1 * c1;
        float h0 = o0 * tanhf_(C0);
        float h1 = o1 * tanhf_(C1);
        uint hp = (uint)f2bf(h0) | (((uint)f2bf(h1)) << 16);
        __hip_atomic_store(
            (uint*)(hbuf + ((size_t)(((cur ^ 1) * 2 + s) * 256 + m0 + ro)) * 512 + j0 + cc0), hp,
            __ATOMIC_RELAXED, SCOPE);
        *(uint*)(hist + (((size_t)s * 128 + t) * 256 + m0 + ro) * 512 + j0 + cc0) = hp;
      }
      __syncthreads();  // drains every thread's vmcnt -> h stores complete at L2/LLC
      // J: publish completion of step t
      if (tid == 0) __hip_atomic_store(fl + cg, (uint)(t + 1), __ATOMIC_RELAXED, SCOPE);
    }
  };

  if (fastCoh) run(BoolC<true>{});
  else run(BoolC<false>{});
}

// ---------------- BN stats ----------------
__global__ void bnstat_k(const ushort* __restrict__ hist,
                         const float* __restrict__ gT, const float* __restrict__ beT,
                         const float* __restrict__ gF, const float* __restrict__ beF,
                         float* __restrict__ scale, float* __restrict__ shift) {
  const int t = blockIdx.x >> 1, s = blockIdx.x & 1;
  const int tid = threadIdx.x;
  const ushort* hp = hist + ((size_t)s * 128 + t) * 256 * 512;
  const float* gp = (s ? gF : gT) + 512;
  const float* bp = (s ? beF : beT) + 512;
#pragma unroll
  for (int hh = 0; hh < 2; ++hh) {
    const int h = tid + hh * 256;
    float sum = 0.f, sq = 0.f;
#pragma unroll 8
    for (int b = 0; b < 256; ++b) {
      float v = bf2f(hp[(size_t)b * 512 + h]);
      sum += v;
      sq += v * v;
    }
    float mu = sum * 0.00390625f;
    float var = sq * 0.00390625f - mu * mu;  // biased, matches reference
    float sc = (1.0f / sqrtf(var + 1e-5f)) * gp[h];
    size_t o = ((size_t)s * 128 + t) * 512 + h;
    scale[o] = sc;
    shift[o] = bp[h] - mu * sc;
  }
}

// ---------------- BN apply + transpose [s][t][b][h] -> out[b][h][t] ----------------
__global__ void bnwrite_k(const ushort* __restrict__ hist, const float* __restrict__ scale,
                          const float* __restrict__ shift, float* __restrict__ out) {
  __shared__ float sT[64 * 129];
  const int bid = blockIdx.x;
  const int hc = bid & 7, b = (bid >> 3) & 255, s = bid >> 11;
  const int h0 = hc * 64;
  const int tid = threadIdx.x;
  const int hh = tid & 63, tq = tid >> 6;
#pragma unroll 4
  for (int tc = 0; tc < 32; ++tc) {
    const int t = tc * 4 + tq;
    const size_t so = ((size_t)s * 128 + t) * 512 + h0 + hh;
    float v = bf2f(hist[(((size_t)s * 128 + t) * 256 + b) * 512 + h0 + hh]);
    sT[hh * 129 + t] = v * scale[so] + shift[so];
  }
  __syncthreads();
  const int t2 = tid & 127, hq = tid >> 7;
#pragma unroll 4
  for (int i = 0; i < 32; ++i) {
    const int h = i * 2 + hq;
    out[(size_t)s * 16777216 + ((size_t)b * 512 + h0 + h) * 128 + t2] = sT[h * 129 + t2];
  }
}

extern "C" void kernel_launch(void* const* d_in, const int* in_sizes, int n_in,
                              void* d_out, int out_size, void* d_ws, size_t ws_size,
                              hipStream_t stream) {
  const float* inputx = (const float*)d_in[0];
  const float* inputy = (const float*)d_in[1];
  const float* WTg = (const float*)d_in[2];
  const float* bTg = (const float*)d_in[3];
  const float* WFg = (const float*)d_in[4];
  const float* bFg = (const float*)d_in[5];
  const float* WTc = (const float*)d_in[6];
  const float* bTc = (const float*)d_in[7];
  const float* WFc = (const float*)d_in[8];
  const float* bFc = (const float*)d_in[9];
  const float* gT = (const float*)d_in[10];
  const float* beT = (const float*)d_in[11];
  const float* gF = (const float*)d_in[12];
  const float* beF = (const float*)d_in[13];
  float* out = (float*)d_out;

  char* ws = (char*)d_ws;
  ushort* xyT = (ushort*)ws;                 // 33,554,432 B
  ushort* hbuf = (ushort*)(ws + 33554432);   //    524,288 B (ping-pong h)
  ushort* hist = (ushort*)(ws + 34603008);   // 67,108,864 B  [s][t][b][h]
  float* scale = (float*)(ws + 101711872);   //    524,288 B
  float* shift = (float*)(ws + 102236160);   //    524,288 B
  uint* bar = (uint*)(ws + 102760448);       //      2,048 B (flags + handshake)

  init_k<<<2, 256, 0, stream>>>(bar);
  xyt_k<<<2048, 256, 0, stream>>>(inputx, inputy, xyT);

  hipFuncSetAttribute((const void*)seq_k, hipFuncAttributeMaxDynamicSharedMemorySize, 116800);
  void* args[12];
  args[0] = &xyT; args[1] = &hbuf; args[2] = &hist;
  args[3] = &WTg; args[4] = &WFg; args[5] = &WTc; args[6] = &WFc;
  args[7] = &bTg; args[8] = &bFg; args[9] = &bTc; args[10] = &bFc;
  args[11] = &bar;
  hipLaunchCooperativeKernel((const void*)seq_k, dim3(NBLK), dim3(NTHR), args, 116800, stream);

  bnstat_k<<<256, 256, 0, stream>>>(hist, gT, beT, gF, beF, scale, shift);
  bnwrite_k<<<4096, 256, 0, stream>>>(hist, scale, shift, out);
}

// Round 6
// 611.564 us; speedup vs baseline: 1.3983x; 1.3983x over previous
//
#include <hip/hip_runtime.h>

#define NBLK 256
#define NTHR 512

typedef __attribute__((ext_vector_type(8))) short s16x8;
typedef __attribute__((ext_vector_type(8))) __bf16 bf16x8;
typedef __attribute__((ext_vector_type(4))) float f32x4;

__device__ __forceinline__ ushort f2bf(float f) {
  uint u = __float_as_uint(f);
  return (ushort)((u + 0x7FFFu + ((u >> 16) & 1u)) >> 16);  // RNE
}
__device__ __forceinline__ float bf2f(ushort s) {
  return __uint_as_float(((uint)s) << 16);
}
__device__ __forceinline__ float sigm(float x) { return 1.f / (1.f + __expf(-x)); }
__device__ __forceinline__ float tanhf_(float x) {
  x = fminf(9.f, fmaxf(-9.f, x));
  float e = __expf(2.f * x);
  return (e - 1.f) / (e + 1.f);
}

// ---------------- init: zero flags ----------------
__global__ void init_k(uint* __restrict__ bar) {
  int i = blockIdx.x * blockDim.x + threadIdx.x;
  if (i < 512) bar[i] = 0u;  // 16 groups x 16 slots (64B/group)
}

// ---------------- transpose/concat x,y -> xyT[t][b][0:512] bf16 (coalesced) ----------------
__global__ void xyt_k(const float* __restrict__ x, const float* __restrict__ y,
                      ushort* __restrict__ xyT) {
  __shared__ ushort sT[64 * 130];
  const int bid = blockIdx.x;      // 2048 = 256 b x 8 chunks
  const int chunk = bid & 7;       // 0..3 -> x, 4..7 -> y
  const int b = bid >> 3;
  const int d0 = (chunk & 3) * 64;
  const float* src = ((chunk < 4) ? x : y) + ((size_t)b * 256 + d0) * 128;
  const int tid = threadIdx.x;
  const int tt = tid & 127, rr = tid >> 7;
#pragma unroll
  for (int i = 0; i < 32; ++i) {
    int row = i * 2 + rr;
    sT[row * 130 + tt] = f2bf(src[(size_t)row * 128 + tt]);
  }
  __syncthreads();
  const int dbase = ((chunk < 4) ? 0 : 256) + d0;
#pragma unroll
  for (int i = 0; i < 16; ++i) {
    int idx = tid + i * 256;
    int t = idx >> 5, j = idx & 31;
    uint v = (uint)sT[(2 * j) * 130 + t] | ((uint)sT[(2 * j + 1) * 130 + t] << 16);
    *(uint*)(xyT + ((size_t)t * 256 + b) * 512 + dbase + 2 * j) = v;
  }
}

// ---------------- persistent sequential LSTM kernel (layer 1 only) ----------------
// bid: mt = bid&7 (row tile), cg = (bid>>3)&15 (colgroup), s = bid>>7 (stream).
// Sync group = 16 blocks sharing (s, mt); flags on one 64B line per group.
// h exchange THROUGH hist only: sc0|sc1 stores + aux=17 load_lds (LLC-coherent).
// Critical-path discipline: h loads issued first, vmcnt(4) waits h only; xy
// prefetch drains later under F/G/H; sAcc barrier is lgkm-only.
// LDS: [0,32K) xybuf0 | [32K,64K) xybuf1 | [64K,96K) hLDS | [96K,+18.4K) sAcc pad-18
__launch_bounds__(NTHR, 2)
__global__ void seq_k(const ushort* __restrict__ xyT,
                      ushort* __restrict__ hist,
                      const float* __restrict__ WTg, const float* __restrict__ WFg,
                      const float* __restrict__ WTc, const float* __restrict__ WFc,
                      const float* __restrict__ bTg, const float* __restrict__ bFg,
                      const float* __restrict__ bTc, const float* __restrict__ bFc,
                      uint* bar) {
  extern __shared__ char smem[];
  float* sAcc = (float*)(smem + 98304);

  const int tid = threadIdx.x;
  const int bid = blockIdx.x;
  const int mt = bid & 7;
  const int cg = (bid >> 3) & 15;
  const int s = bid >> 7;
  const int g = s * 8 + mt;
  const int m0 = mt * 32;
  const int j0 = cg * 32;
  const int w = tid >> 6;
  const int l = tid & 63;
  const int l15 = l & 15;
  const int q16 = (l >> 4) * 16;  // byte offset of k-octet
  const bool isGate = (w < 6);
  uint* fl = bar + (g << 4);

  // ---- persistent weight fragments in VGPRs (layer 1 = offset 1) ----
  s16x8 wreg[32];
  if (isGate) {
    const int gt = w >> 1, half = w & 1;
    const float* Wp = ((s == 0) ? WTg : WFg) + 1572864
                    + ((size_t)(gt * 512 + j0 + half * 16 + l15)) * 1024 + (q16 >> 1);
#pragma unroll
    for (int kk = 0; kk < 32; ++kk) {
      s16x8 v;
#pragma unroll
      for (int e = 0; e < 8; ++e) v[e] = (short)f2bf(Wp[kk * 32 + e]);
      wreg[kk] = v;
    }
  } else {
    const int half = w & 1;
    const float* Wp = ((s == 0) ? WTc : WFc) + 393216
                    + ((size_t)(j0 + half * 16 + l15)) * 768 + (q16 >> 1);
#pragma unroll
    for (int kk = 0; kk < 24; ++kk) {
      s16x8 v;
#pragma unroll
      for (int e = 0; e < 8; ++e) v[e] = (short)f2bf(Wp[kk * 32 + e]);
      wreg[kk] = v;
    }
  }

  // ---- per-thread elementwise constants + register-resident cell state ----
  const int ro = tid >> 4;         // row 0..31
  const int cc0 = (tid & 15) * 2;  // col pair
  const int ehalf = cc0 >> 4;
  const int ec16 = cc0 & 15;
  float bfv0, bfv1, biv0, biv1, bov0, bov1, bcv0, bcv1;
  {
    const float* bg = ((s == 0) ? bTg : bFg) + 1536;
    const float* bc = ((s == 0) ? bTc : bFc) + 512;
    int col = j0 + cc0;
    bfv0 = bg[col];        bfv1 = bg[col + 1];
    biv0 = bg[512 + col];  biv1 = bg[513 + col];
    bov0 = bg[1024 + col]; bov1 = bg[1025 + col];
    bcv0 = bc[col];        bcv1 = bc[col + 1];
  }
  float C0 = 0.f, C1 = 0.f;

  // stage one 1024B row; XOR-swizzled source, linear LDS dest
  auto stage_row = [&](const ushort* gbase, char* lbase, int r) {
    const char* srow = (const char*)(gbase + (size_t)r * 512);
    int off = (l * 16) ^ ((r & 7) << 4);
    __builtin_amdgcn_global_load_lds(
        (const __attribute__((address_space(1))) void*)(srow + off),
        (__attribute__((address_space(3))) void*)(lbase + (r << 10)), 16, 0, 0);
  };
  auto stage_row_coh = [&](const ushort* gbase, char* lbase, int r) {
    const char* srow = (const char*)(gbase + (size_t)r * 512);
    int off = (l * 16) ^ ((r & 7) << 4);
    __builtin_amdgcn_global_load_lds(
        (const __attribute__((address_space(1))) void*)(srow + off),
        (__attribute__((address_space(3))) void*)(lbase + (r << 10)), 16, 0, 17);  // sc0|sc1
  };

  // prestage xy(0) into buf0
  {
#pragma unroll
    for (int i = 0; i < 4; ++i) stage_row(xyT + (size_t)m0 * 512, smem, (w << 2) + i);
  }
  __syncthreads();

  const int sw = (l15 & 7) << 4;
  for (int t = 0; t < 128; ++t) {
    const int cur = t & 1;
    char* xyb = smem + cur * 32768;
    char* xybn = smem + (cur ^ 1) * 32768;
    char* hb = smem + 65536;

    f32x4 acc0 = {0.f, 0.f, 0.f, 0.f};
    f32x4 acc1 = {0.f, 0.f, 0.f, 0.f};

    // A: xy-half MFMAs (data staged last step; no cross-block dependency)
    {
      const char* base0 = xyb + (l15 << 10);
      const char* base1 = xyb + ((16 + l15) << 10);
      if (isGate) {
#pragma unroll
        for (int kk = 0; kk < 16; ++kk) {
          int c2 = (kk * 64 + q16) ^ sw;
          s16x8 a0 = *(const s16x8*)(base0 + c2);
          s16x8 a1 = *(const s16x8*)(base1 + c2);
          acc0 = __builtin_amdgcn_mfma_f32_16x16x32_bf16(
              __builtin_bit_cast(bf16x8, a0), __builtin_bit_cast(bf16x8, wreg[kk]), acc0, 0, 0, 0);
          acc1 = __builtin_amdgcn_mfma_f32_16x16x32_bf16(
              __builtin_bit_cast(bf16x8, a1), __builtin_bit_cast(bf16x8, wreg[kk]), acc1, 0, 0, 0);
        }
      } else {
#pragma unroll
        for (int kk = 0; kk < 8; ++kk) {
          int c2 = ((s * 512 + kk * 64 + q16)) ^ sw;
          s16x8 a0 = *(const s16x8*)(base0 + c2);
          s16x8 a1 = *(const s16x8*)(base1 + c2);
          acc0 = __builtin_amdgcn_mfma_f32_16x16x32_bf16(
              __builtin_bit_cast(bf16x8, a0), __builtin_bit_cast(bf16x8, wreg[kk]), acc0, 0, 0, 0);
          acc1 = __builtin_amdgcn_mfma_f32_16x16x32_bf16(
              __builtin_bit_cast(bf16x8, a1), __builtin_bit_cast(bf16x8, wreg[kk]), acc1, 0, 0, 0);
        }
      }
    }

    // C: wave 0 only: relaxed system-scope poll of the 16 group flags
    if (w == 0 && t) {
      const uint tgt = (uint)t;
      while (true) {
        uint v = (l < 16)
                     ? __hip_atomic_load(fl + l, __ATOMIC_RELAXED, __HIP_MEMORY_SCOPE_SYSTEM)
                     : tgt;
        if (__all((int)(v >= tgt))) break;
        __builtin_amdgcn_s_sleep(1);
      }
    }
    __builtin_amdgcn_s_barrier();  // bar1: release other waves once peers are done

    // D: h loads FIRST (critical), then xy(t+1) prefetch (drains later)
    if (t) {
      const ushort* hsrc = hist + (((size_t)s * 128 + (t - 1)) * 256 + m0) * 512;
#pragma unroll
      for (int i = 0; i < 4; ++i) stage_row_coh(hsrc, hb, (w << 2) + i);
    }
    {
      const int tn = (t < 127) ? t + 1 : 127;
      const ushort* xyNext = xyT + ((size_t)(tn * 256 + m0)) * 512;
#pragma unroll
      for (int i = 0; i < 4; ++i) stage_row(xyNext, xybn, (w << 2) + i);
    }

    // bar2: wait h loads only (oldest 4); xy stays in flight
    asm volatile("s_waitcnt vmcnt(4)" ::: "memory");
    __builtin_amdgcn_sched_barrier(0);
    __builtin_amdgcn_s_barrier();
    __builtin_amdgcn_sched_barrier(0);

    // F: h-half MFMAs (skipped at t=0: h(0)=0)
    if (t) {
      const char* base0 = hb + (l15 << 10);
      const char* base1 = hb + ((16 + l15) << 10);
      if (isGate) {
#pragma unroll
        for (int kk = 0; kk < 16; ++kk) {
          int c2 = (kk * 64 + q16) ^ sw;
          s16x8 a0 = *(const s16x8*)(base0 + c2);
          s16x8 a1 = *(const s16x8*)(base1 + c2);
          acc0 = __builtin_amdgcn_mfma_f32_16x16x32_bf16(
              __builtin_bit_cast(bf16x8, a0), __builtin_bit_cast(bf16x8, wreg[16 + kk]), acc0, 0, 0, 0);
          acc1 = __builtin_amdgcn_mfma_f32_16x16x32_bf16(
              __builtin_bit_cast(bf16x8, a1), __builtin_bit_cast(bf16x8, wreg[16 + kk]), acc1, 0, 0, 0);
        }
      } else {
#pragma unroll
        for (int kk = 0; kk < 16; ++kk) {
          int c2 = (kk * 64 + q16) ^ sw;
          s16x8 a0 = *(const s16x8*)(base0 + c2);
          s16x8 a1 = *(const s16x8*)(base1 + c2);
          acc0 = __builtin_amdgcn_mfma_f32_16x16x32_bf16(
              __builtin_bit_cast(bf16x8, a0), __builtin_bit_cast(bf16x8, wreg[8 + kk]), acc0, 0, 0, 0);
          acc1 = __builtin_amdgcn_mfma_f32_16x16x32_bf16(
              __builtin_bit_cast(bf16x8, a1), __builtin_bit_cast(bf16x8, wreg[8 + kk]), acc1, 0, 0, 0);
        }
      }
    }

    // G: acc -> sAcc (row stride 18 floats)
#pragma unroll
    for (int rg = 0; rg < 4; ++rg) {
      sAcc[w * 576 + ((q16 >> 2) + rg) * 18 + l15] = acc0[rg];
      sAcc[w * 576 + (16 + (q16 >> 2) + rg) * 18 + l15] = acc1[rg];
    }
    // bar3: LDS-only drain (keep xy loads in flight)
    asm volatile("s_waitcnt lgkmcnt(0)" ::: "memory");
    __builtin_amdgcn_sched_barrier(0);
    __builtin_amdgcn_s_barrier();
    __builtin_amdgcn_sched_barrier(0);

    // H: elementwise LSTM update (C in registers); single coherent store to hist
    {
      const float2 pf = *(const float2*)&sAcc[(0 + ehalf) * 576 + ro * 18 + ec16];
      const float2 pi = *(const float2*)&sAcc[(2 + ehalf) * 576 + ro * 18 + ec16];
      const float2 po = *(const float2*)&sAcc[(4 + ehalf) * 576 + ro * 18 + ec16];
      const float2 pc = *(const float2*)&sAcc[(6 + ehalf) * 576 + ro * 18 + ec16];
      float f0 = sigm(pf.x + bfv0), f1 = sigm(pf.y + bfv1);
      float i0 = sigm(pi.x + biv0), i1 = sigm(pi.y + biv1);
      float o0 = sigm(po.x + bov0), o1 = sigm(po.y + bov1);
      float c0 = tanhf_(pc.x + bcv0), c1 = tanhf_(pc.y + bcv1);
      C0 = f0 * C0 + i0 * c0;
      C1 = f1 * C1 + i1 * c1;
      float h0 = o0 * tanhf_(C0);
      float h1 = o1 * tanhf_(C1);
      uint hp = (uint)f2bf(h0) | (((uint)f2bf(h1)) << 16);
      __hip_atomic_store(
          (uint*)(hist + (((size_t)s * 128 + t) * 256 + m0 + ro) * 512 + j0 + cc0), hp,
          __ATOMIC_RELAXED, __HIP_MEMORY_SCOPE_SYSTEM);
    }
    __syncthreads();  // bar4: full drain (hist store acks + xy prefetch) before publish
    // J: publish completion of step t
    if (tid == 0)
      __hip_atomic_store(fl + cg, (uint)(t + 1), __ATOMIC_RELAXED, __HIP_MEMORY_SCOPE_SYSTEM);
  }
}

// ---------------- BN stats ----------------
__global__ void bnstat_k(const ushort* __restrict__ hist,
                         const float* __restrict__ gT, const float* __restrict__ beT,
                         const float* __restrict__ gF, const float* __restrict__ beF,
                         float* __restrict__ scale, float* __restrict__ shift) {
  const int t = blockIdx.x >> 1, s = blockIdx.x & 1;
  const int tid = threadIdx.x;
  const ushort* hp = hist + ((size_t)s * 128 + t) * 256 * 512;
  const float* gp = (s ? gF : gT) + 512;
  const float* bp = (s ? beF : beT) + 512;
#pragma unroll
  for (int hh = 0; hh < 2; ++hh) {
    const int h = tid + hh * 256;
    float sum = 0.f, sq = 0.f;
#pragma unroll 8
    for (int b = 0; b < 256; ++b) {
      float v = bf2f(hp[(size_t)b * 512 + h]);
      sum += v;
      sq += v * v;
    }
    float mu = sum * 0.00390625f;
    float var = sq * 0.00390625f - mu * mu;  // biased, matches reference
    float sc = (1.0f / sqrtf(var + 1e-5f)) * gp[h];
    size_t o = ((size_t)s * 128 + t) * 512 + h;
    scale[o] = sc;
    shift[o] = bp[h] - mu * sc;
  }
}

// ---------------- BN apply + transpose [s][t][b][h] -> out[b][h][t] ----------------
__global__ void bnwrite_k(const ushort* __restrict__ hist, const float* __restrict__ scale,
                          const float* __restrict__ shift, float* __restrict__ out) {
  __shared__ float sT[64 * 129];
  const int bid = blockIdx.x;
  const int hc = bid & 7, b = (bid >> 3) & 255, s = bid >> 11;
  const int h0 = hc * 64;
  const int tid = threadIdx.x;
  const int hh = tid & 63, tq = tid >> 6;
#pragma unroll 4
  for (int tc = 0; tc < 32; ++tc) {
    const int t = tc * 4 + tq;
    const size_t so = ((size_t)s * 128 + t) * 512 + h0 + hh;
    float v = bf2f(hist[(((size_t)s * 128 + t) * 256 + b) * 512 + h0 + hh]);
    sT[hh * 129 + t] = v * scale[so] + shift[so];
  }
  __syncthreads();
  const int t2 = tid & 127, hq = tid >> 7;
#pragma unroll 4
  for (int i = 0; i < 32; ++i) {
    const int h = i * 2 + hq;
    out[(size_t)s * 16777216 + ((size_t)b * 512 + h0 + h) * 128 + t2] = sT[h * 129 + t2];
  }
}

extern "C" void kernel_launch(void* const* d_in, const int* in_sizes, int n_in,
                              void* d_out, int out_size, void* d_ws, size_t ws_size,
                              hipStream_t stream) {
  const float* inputx = (const float*)d_in[0];
  const float* inputy = (const float*)d_in[1];
  const float* WTg = (const float*)d_in[2];
  const float* bTg = (const float*)d_in[3];
  const float* WFg = (const float*)d_in[4];
  const float* bFg = (const float*)d_in[5];
  const float* WTc = (const float*)d_in[6];
  const float* bTc = (const float*)d_in[7];
  const float* WFc = (const float*)d_in[8];
  const float* bFc = (const float*)d_in[9];
  const float* gT = (const float*)d_in[10];
  const float* beT = (const float*)d_in[11];
  const float* gF = (const float*)d_in[12];
  const float* beF = (const float*)d_in[13];
  float* out = (float*)d_out;

  char* ws = (char*)d_ws;
  ushort* xyT = (ushort*)ws;                 // 33,554,432 B
  ushort* hist = (ushort*)(ws + 34603008);   // 67,108,864 B  [s][t][b][h]
  float* scale = (float*)(ws + 101711872);   //    524,288 B
  float* shift = (float*)(ws + 102236160);   //    524,288 B
  uint* bar = (uint*)(ws + 102760448);       //      2,048 B (flags)

  init_k<<<2, 256, 0, stream>>>(bar);
  xyt_k<<<2048, 256, 0, stream>>>(inputx, inputy, xyT);

  hipFuncSetAttribute((const void*)seq_k, hipFuncAttributeMaxDynamicSharedMemorySize, 116736);
  void* args[11];
  args[0] = &xyT; args[1] = &hist;
  args[2] = &WTg; args[3] = &WFg; args[4] = &WTc; args[5] = &WFc;
  args[6] = &bTg; args[7] = &bFg; args[8] = &bTc; args[9] = &bFc;
  args[10] = &bar;
  hipLaunchCooperativeKernel((const void*)seq_k, dim3(NBLK), dim3(NTHR), args, 116736, stream);

  bnstat_k<<<256, 256, 0, stream>>>(hist, gT, beT, gF, beF, scale, shift);
  bnwrite_k<<<4096, 256, 0, stream>>>(hist, scale, shift, out);
}

// Round 7
// 543.865 us; speedup vs baseline: 1.5723x; 1.1245x over previous
//
#include <hip/hip_runtime.h>

#define NBLK 256
#define NTHR 512

typedef __attribute__((ext_vector_type(8))) short s16x8;
typedef __attribute__((ext_vector_type(8))) __bf16 bf16x8;
typedef __attribute__((ext_vector_type(4))) float f32x4;

__device__ __forceinline__ ushort f2bf(float f) {
  uint u = __float_as_uint(f);
  return (ushort)((u + 0x7FFFu + ((u >> 16) & 1u)) >> 16);  // RNE
}
__device__ __forceinline__ float bf2f(ushort s) {
  return __uint_as_float(((uint)s) << 16);
}
__device__ __forceinline__ float sigm(float x) { return 1.f / (1.f + __expf(-x)); }
__device__ __forceinline__ float tanhf_(float x) {
  x = fminf(9.f, fmaxf(-9.f, x));
  float e = __expf(2.f * x);
  return (e - 1.f) / (e + 1.f);
}

#define MFMA(a, b, c) __builtin_amdgcn_mfma_f32_16x16x32_bf16( \
    __builtin_bit_cast(bf16x8, a), __builtin_bit_cast(bf16x8, b), c, 0, 0, 0)

// ---------------- init: zero flags ----------------
__global__ void init_k(uint* __restrict__ bar) {
  int i = blockIdx.x * blockDim.x + threadIdx.x;
  if (i < 512) bar[i] = 0u;
}

// ---------------- transpose/concat x,y -> xyT[t][b][0:512] bf16 (coalesced) ----------------
__global__ void xyt_k(const float* __restrict__ x, const float* __restrict__ y,
                      ushort* __restrict__ xyT) {
  __shared__ ushort sT[64 * 130];
  const int bid = blockIdx.x;      // 2048 = 256 b x 8 chunks
  const int chunk = bid & 7;       // 0..3 -> x, 4..7 -> y
  const int b = bid >> 3;
  const int d0 = (chunk & 3) * 64;
  const float* src = ((chunk < 4) ? x : y) + ((size_t)b * 256 + d0) * 128;
  const int tid = threadIdx.x;
  const int tt = tid & 127, rr = tid >> 7;
#pragma unroll
  for (int i = 0; i < 32; ++i) {
    int row = i * 2 + rr;
    sT[row * 130 + tt] = f2bf(src[(size_t)row * 128 + tt]);
  }
  __syncthreads();
  const int dbase = ((chunk < 4) ? 0 : 256) + d0;
#pragma unroll
  for (int i = 0; i < 16; ++i) {
    int idx = tid + i * 256;
    int t = idx >> 5, j = idx & 31;
    uint v = (uint)sT[(2 * j) * 130 + t] | ((uint)sT[(2 * j + 1) * 130 + t] << 16);
    *(uint*)(xyT + ((size_t)t * 256 + b) * 512 + dbase + 2 * j) = v;
  }
}

// ---------------- persistent sequential LSTM kernel (layer 1 only) ----------------
// bid: mt = bid&7 (row tile), cg = (bid>>3)&15 (colgroup), s = bid>>7 (stream).
// Wave layout (A-reuse): w<6: gate g=w>>1 (f,i,o), K-half kh=w&1, 32 cols (2 panels);
//                        w>=6: candidate, K-half kh=w&1.
// Each wave: per kk read a0/a1 once -> 4 MFMAs (2 panels x 2 Mtiles).
// K-half partials summed from two sAcc slots in the elementwise phase.
// h exchange through hist: sc0|sc1 stores + aux=17 load_lds (LLC-coherent).
// LDS: [0,32K) xybuf0 | [32K,64K) xybuf1 | [64K,96K) hLDS | [96K,+34816) sAcc
__launch_bounds__(NTHR, 2)
__global__ void seq_k(const ushort* __restrict__ xyT,
                      ushort* __restrict__ hist,
                      const float* __restrict__ WTg, const float* __restrict__ WFg,
                      const float* __restrict__ WTc, const float* __restrict__ WFc,
                      const float* __restrict__ bTg, const float* __restrict__ bFg,
                      const float* __restrict__ bTc, const float* __restrict__ bFc,
                      uint* bar) {
  extern __shared__ char smem[];
  float* sAcc = (float*)(smem + 98304);  // 8 slots x [32 rows x stride 34] f32

  const int tid = threadIdx.x;
  const int bid = blockIdx.x;
  const int mt = bid & 7;
  const int cg = (bid >> 3) & 15;
  const int s = bid >> 7;
  const int g = s * 8 + mt;
  const int m0 = mt * 32;
  const int j0 = cg * 32;
  const int w = tid >> 6;
  const int l = tid & 63;
  const int l15 = l & 15;
  const int q16 = (l >> 4) * 16;  // byte offset of k-octet
  const bool isGate = (w < 6);
  const int kh = w & 1;
  uint* fl = bar + (g << 4);

  // ---- persistent weight fragments in VGPRs (layer 1 = offset 1) ----
  // gate wave (g=w>>1, kh): wreg[p][kk]: kk<8 xy-K (k=kh*256+kk*32), kk>=8 h-K (k=512+kh*256+(kk-8)*32)
  // cand wave (kh): wreg[p][kk]: kk<4 xy-K (k=kh*128+kk*32), kk in 4..12 h-K (k=256+kh*256+(kk-4)*32)
  s16x8 wreg[2][16];
  if (isGate) {
    const int gt = w >> 1;
#pragma unroll
    for (int p = 0; p < 2; ++p) {
      const float* Wrow = ((s == 0) ? WTg : WFg) + 1572864
                        + ((size_t)(gt * 512 + j0 + p * 16 + l15)) * 1024 + (q16 >> 1);
#pragma unroll
      for (int kk = 0; kk < 8; ++kk) {
        s16x8 v;
#pragma unroll
        for (int e = 0; e < 8; ++e) v[e] = (short)f2bf(Wrow[kh * 256 + kk * 32 + e]);
        wreg[p][kk] = v;
      }
#pragma unroll
      for (int kk = 0; kk < 8; ++kk) {
        s16x8 v;
#pragma unroll
        for (int e = 0; e < 8; ++e) v[e] = (short)f2bf(Wrow[512 + kh * 256 + kk * 32 + e]);
        wreg[p][8 + kk] = v;
      }
    }
  } else {
#pragma unroll
    for (int p = 0; p < 2; ++p) {
      const float* Wrow = ((s == 0) ? WTc : WFc) + 393216
                        + ((size_t)(j0 + p * 16 + l15)) * 768 + (q16 >> 1);
#pragma unroll
      for (int kk = 0; kk < 4; ++kk) {
        s16x8 v;
#pragma unroll
        for (int e = 0; e < 8; ++e) v[e] = (short)f2bf(Wrow[kh * 128 + kk * 32 + e]);
        wreg[p][kk] = v;
      }
#pragma unroll
      for (int kk = 0; kk < 8; ++kk) {
        s16x8 v;
#pragma unroll
        for (int e = 0; e < 8; ++e) v[e] = (short)f2bf(Wrow[256 + kh * 256 + kk * 32 + e]);
        wreg[p][4 + kk] = v;
      }
    }
  }

  // ---- per-thread elementwise constants + register-resident cell state ----
  const int ro = tid >> 4;         // row 0..31
  const int cc0 = (tid & 15) * 2;  // col 0..30 even
  float bfv0, bfv1, biv0, biv1, bov0, bov1, bcv0, bcv1;
  {
    const float* bg = ((s == 0) ? bTg : bFg) + 1536;
    const float* bc = ((s == 0) ? bTc : bFc) + 512;
    int col = j0 + cc0;
    bfv0 = bg[col];        bfv1 = bg[col + 1];
    biv0 = bg[512 + col];  biv1 = bg[513 + col];
    bov0 = bg[1024 + col]; bov1 = bg[1025 + col];
    bcv0 = bc[col];        bcv1 = bc[col + 1];
  }
  float C0 = 0.f, C1 = 0.f;

  // stage one 1024B row; XOR-swizzled source, linear LDS dest
  auto stage_row = [&](const ushort* gbase, char* lbase, int r) {
    const char* srow = (const char*)(gbase + (size_t)r * 512);
    int off = (l * 16) ^ ((r & 7) << 4);
    __builtin_amdgcn_global_load_lds(
        (const __attribute__((address_space(1))) void*)(srow + off),
        (__attribute__((address_space(3))) void*)(lbase + (r << 10)), 16, 0, 0);
  };
  auto stage_row_coh = [&](const ushort* gbase, char* lbase, int r) {
    const char* srow = (const char*)(gbase + (size_t)r * 512);
    int off = (l * 16) ^ ((r & 7) << 4);
    __builtin_amdgcn_global_load_lds(
        (const __attribute__((address_space(1))) void*)(srow + off),
        (__attribute__((address_space(3))) void*)(lbase + (r << 10)), 16, 0, 17);  // sc0|sc1
  };

  // prestage xy(0) into buf0
  {
#pragma unroll
    for (int i = 0; i < 4; ++i) stage_row(xyT + (size_t)m0 * 512, smem, (w << 2) + i);
  }
  __syncthreads();

  const int sw = (l15 & 7) << 4;
  for (int t = 0; t < 128; ++t) {
    const int cur = t & 1;
    char* xyb = smem + cur * 32768;
    char* xybn = smem + (cur ^ 1) * 32768;
    char* hb = smem + 65536;

    f32x4 acc00 = {0.f, 0.f, 0.f, 0.f};  // panel0, mtile0
    f32x4 acc01 = {0.f, 0.f, 0.f, 0.f};  // panel0, mtile1
    f32x4 acc10 = {0.f, 0.f, 0.f, 0.f};  // panel1, mtile0
    f32x4 acc11 = {0.f, 0.f, 0.f, 0.f};  // panel1, mtile1

    // A: xy-half MFMAs (data staged last step; no cross-block dependency)
    {
      const char* base0 = xyb + (l15 << 10);
      const char* base1 = xyb + ((16 + l15) << 10);
      if (isGate) {
#pragma unroll
        for (int kk = 0; kk < 8; ++kk) {
          int c2 = (kh * 512 + kk * 64 + q16) ^ sw;
          s16x8 a0 = *(const s16x8*)(base0 + c2);
          s16x8 a1 = *(const s16x8*)(base1 + c2);
          acc00 = MFMA(a0, wreg[0][kk], acc00);
          acc01 = MFMA(a1, wreg[0][kk], acc01);
          acc10 = MFMA(a0, wreg[1][kk], acc10);
          acc11 = MFMA(a1, wreg[1][kk], acc11);
        }
      } else {
#pragma unroll
        for (int kk = 0; kk < 4; ++kk) {
          int c2 = (s * 512 + kh * 256 + kk * 64 + q16) ^ sw;
          s16x8 a0 = *(const s16x8*)(base0 + c2);
          s16x8 a1 = *(const s16x8*)(base1 + c2);
          acc00 = MFMA(a0, wreg[0][kk], acc00);
          acc01 = MFMA(a1, wreg[0][kk], acc01);
          acc10 = MFMA(a0, wreg[1][kk], acc10);
          acc11 = MFMA(a1, wreg[1][kk], acc11);
        }
      }
    }

    // C: wave 0 only: relaxed system-scope poll of the 16 group flags
    if (w == 0 && t) {
      const uint tgt = (uint)t;
      while (true) {
        uint v = (l < 16)
                     ? __hip_atomic_load(fl + l, __ATOMIC_RELAXED, __HIP_MEMORY_SCOPE_SYSTEM)
                     : tgt;
        if (__all((int)(v >= tgt))) break;
        __builtin_amdgcn_s_sleep(1);
      }
    }
    __builtin_amdgcn_s_barrier();  // bar1: release other waves once peers are done

    // D: h loads FIRST (critical), then xy(t+1) prefetch (drains later)
    if (t) {
      const ushort* hsrc = hist + (((size_t)s * 128 + (t - 1)) * 256 + m0) * 512;
#pragma unroll
      for (int i = 0; i < 4; ++i) stage_row_coh(hsrc, hb, (w << 2) + i);
    }
    {
      const int tn = (t < 127) ? t + 1 : 127;
      const ushort* xyNext = xyT + ((size_t)(tn * 256 + m0)) * 512;
#pragma unroll
      for (int i = 0; i < 4; ++i) stage_row(xyNext, xybn, (w << 2) + i);
    }

    // bar2: wait h loads only (oldest 4); xy stays in flight
    asm volatile("s_waitcnt vmcnt(4)" ::: "memory");
    __builtin_amdgcn_sched_barrier(0);
    __builtin_amdgcn_s_barrier();
    __builtin_amdgcn_sched_barrier(0);

    // F: h-half MFMAs (skipped at t=0: h(0)=0)
    if (t) {
      const char* base0 = hb + (l15 << 10);
      const char* base1 = hb + ((16 + l15) << 10);
      if (isGate) {
#pragma unroll
        for (int kk = 0; kk < 8; ++kk) {
          int c2 = (kh * 512 + kk * 64 + q16) ^ sw;
          s16x8 a0 = *(const s16x8*)(base0 + c2);
          s16x8 a1 = *(const s16x8*)(base1 + c2);
          acc00 = MFMA(a0, wreg[0][8 + kk], acc00);
          acc01 = MFMA(a1, wreg[0][8 + kk], acc01);
          acc10 = MFMA(a0, wreg[1][8 + kk], acc10);
          acc11 = MFMA(a1, wreg[1][8 + kk], acc11);
        }
      } else {
#pragma unroll
        for (int kk = 0; kk < 8; ++kk) {
          int c2 = (kh * 512 + kk * 64 + q16) ^ sw;
          s16x8 a0 = *(const s16x8*)(base0 + c2);
          s16x8 a1 = *(const s16x8*)(base1 + c2);
          acc00 = MFMA(a0, wreg[0][4 + kk], acc00);
          acc01 = MFMA(a1, wreg[0][4 + kk], acc01);
          acc10 = MFMA(a0, wreg[1][4 + kk], acc10);
          acc11 = MFMA(a1, wreg[1][4 + kk], acc11);
        }
      }
    }

    // G: acc -> sAcc slot w (row stride 34 f32, slot 1088 f32)
    {
      float* sl = sAcc + w * 1088 + l15;
      const int r0 = q16 >> 2;  // (l>>4)*4
#pragma unroll
      for (int rg = 0; rg < 4; ++rg) {
        sl[(r0 + rg) * 34] = acc00[rg];
        sl[(16 + r0 + rg) * 34] = acc01[rg];
        sl[(r0 + rg) * 34 + 16] = acc10[rg];
        sl[(16 + r0 + rg) * 34 + 16] = acc11[rg];
      }
    }
    // bar3: LDS-only drain (keep xy loads in flight)
    asm volatile("s_waitcnt lgkmcnt(0)" ::: "memory");
    __builtin_amdgcn_sched_barrier(0);
    __builtin_amdgcn_s_barrier();
    __builtin_amdgcn_sched_barrier(0);

    // H: elementwise LSTM update; K-half partials summed here
    {
      const int eb = ro * 34 + cc0;
      float2 f0v = *(const float2*)&sAcc[eb];
      float2 f1v = *(const float2*)&sAcc[1088 + eb];
      float2 i0v = *(const float2*)&sAcc[2176 + eb];
      float2 i1v = *(const float2*)&sAcc[3264 + eb];
      float2 o0v = *(const float2*)&sAcc[4352 + eb];
      float2 o1v = *(const float2*)&sAcc[5440 + eb];
      float2 c0v = *(const float2*)&sAcc[6528 + eb];
      float2 c1v = *(const float2*)&sAcc[7616 + eb];
      float f0 = sigm(f0v.x + f1v.x + bfv0), f1 = sigm(f0v.y + f1v.y + bfv1);
      float i0 = sigm(i0v.x + i1v.x + biv0), i1 = sigm(i0v.y + i1v.y + biv1);
      float o0 = sigm(o0v.x + o1v.x + bov0), o1 = sigm(o0v.y + o1v.y + bov1);
      float c0 = tanhf_(c0v.x + c1v.x + bcv0), c1 = tanhf_(c0v.y + c1v.y + bcv1);
      C0 = f0 * C0 + i0 * c0;
      C1 = f1 * C1 + i1 * c1;
      float h0 = o0 * tanhf_(C0);
      float h1 = o1 * tanhf_(C1);
      uint hp = (uint)f2bf(h0) | (((uint)f2bf(h1)) << 16);
      __hip_atomic_store(
          (uint*)(hist + (((size_t)s * 128 + t) * 256 + m0 + ro) * 512 + j0 + cc0), hp,
          __ATOMIC_RELAXED, __HIP_MEMORY_SCOPE_SYSTEM);
    }
    __syncthreads();  // bar4: full drain (hist store acks + xy prefetch) before publish
    // J: publish completion of step t
    if (tid == 0)
      __hip_atomic_store(fl + cg, (uint)(t + 1), __ATOMIC_RELAXED, __HIP_MEMORY_SCOPE_SYSTEM);
  }
}

// ---------------- BN stats ----------------
__global__ void bnstat_k(const ushort* __restrict__ hist,
                         const float* __restrict__ gT, const float* __restrict__ beT,
                         const float* __restrict__ gF, const float* __restrict__ beF,
                         float* __restrict__ scale, float* __restrict__ shift) {
  const int t = blockIdx.x >> 1, s = blockIdx.x & 1;
  const int tid = threadIdx.x;
  const ushort* hp = hist + ((size_t)s * 128 + t) * 256 * 512;
  const float* gp = (s ? gF : gT) + 512;
  const float* bp = (s ? beF : beT) + 512;
#pragma unroll
  for (int hh = 0; hh < 2; ++hh) {
    const int h = tid + hh * 256;
    float sum = 0.f, sq = 0.f;
#pragma unroll 8
    for (int b = 0; b < 256; ++b) {
      float v = bf2f(hp[(size_t)b * 512 + h]);
      sum += v;
      sq += v * v;
    }
    float mu = sum * 0.00390625f;
    float var = sq * 0.00390625f - mu * mu;  // biased, matches reference
    float sc = (1.0f / sqrtf(var + 1e-5f)) * gp[h];
    size_t o = ((size_t)s * 128 + t) * 512 + h;
    scale[o] = sc;
    shift[o] = bp[h] - mu * sc;
  }
}

// ---------------- BN apply + transpose [s][t][b][h] -> out[b][h][t] ----------------
__global__ void bnwrite_k(const ushort* __restrict__ hist, const float* __restrict__ scale,
                          const float* __restrict__ shift, float* __restrict__ out) {
  __shared__ float sT[64 * 129];
  const int bid = blockIdx.x;
  const int hc = bid & 7, b = (bid >> 3) & 255, s = bid >> 11;
  const int h0 = hc * 64;
  const int tid = threadIdx.x;
  const int hh = tid & 63, tq = tid >> 6;
#pragma unroll 4
  for (int tc = 0; tc < 32; ++tc) {
    const int t = tc * 4 + tq;
    const size_t so = ((size_t)s * 128 + t) * 512 + h0 + hh;
    float v = bf2f(hist[(((size_t)s * 128 + t) * 256 + b) * 512 + h0 + hh]);
    sT[hh * 129 + t] = v * scale[so] + shift[so];
  }
  __syncthreads();
  const int t2 = tid & 127, hq = tid >> 7;
#pragma unroll 4
  for (int i = 0; i < 32; ++i) {
    const int h = i * 2 + hq;
    out[(size_t)s * 16777216 + ((size_t)b * 512 + h0 + h) * 128 + t2] = sT[h * 129 + t2];
  }
}

extern "C" void kernel_launch(void* const* d_in, const int* in_sizes, int n_in,
                              void* d_out, int out_size, void* d_ws, size_t ws_size,
                              hipStream_t stream) {
  const float* inputx = (const float*)d_in[0];
  const float* inputy = (const float*)d_in[1];
  const float* WTg = (const float*)d_in[2];
  const float* bTg = (const float*)d_in[3];
  const float* WFg = (const float*)d_in[4];
  const float* bFg = (const float*)d_in[5];
  const float* WTc = (const float*)d_in[6];
  const float* bTc = (const float*)d_in[7];
  const float* WFc = (const float*)d_in[8];
  const float* bFc = (const float*)d_in[9];
  const float* gT = (const float*)d_in[10];
  const float* beT = (const float*)d_in[11];
  const float* gF = (const float*)d_in[12];
  const float* beF = (const float*)d_in[13];
  float* out = (float*)d_out;

  char* ws = (char*)d_ws;
  ushort* xyT = (ushort*)ws;                 // 33,554,432 B
  ushort* hist = (ushort*)(ws + 34603008);   // 67,108,864 B  [s][t][b][h]
  float* scale = (float*)(ws + 101711872);   //    524,288 B
  float* shift = (float*)(ws + 102236160);   //    524,288 B
  uint* bar = (uint*)(ws + 102760448);       //      2,048 B (flags)

  init_k<<<2, 256, 0, stream>>>(bar);
  xyt_k<<<2048, 256, 0, stream>>>(inputx, inputy, xyT);

  hipFuncSetAttribute((const void*)seq_k, hipFuncAttributeMaxDynamicSharedMemorySize, 133120);
  void* args[11];
  args[0] = &xyT; args[1] = &hist;
  args[2] = &WTg; args[3] = &WFg; args[4] = &WTc; args[5] = &WFc;
  args[6] = &bTg; args[7] = &bFg; args[8] = &bTc; args[9] = &bFc;
  args[10] = &bar;
  hipLaunchCooperativeKernel((const void*)seq_k, dim3(NBLK), dim3(NTHR), args, 133120, stream);

  bnstat_k<<<256, 256, 0, stream>>>(hist, gT, beT, gF, beF, scale, shift);
  bnwrite_k<<<4096, 256, 0, stream>>>(hist, scale, shift, out);
}